// Round 3
// baseline (243.979 us; speedup 1.0000x reference)
//
#include <hip/hip_runtime.h>
#include <math.h>

// img (16,8,512,512) fp32, params (16,3) fp32, out (16,8,512,512) fp32.
// Round 3: attack the two half-busy pipes found in round 2 (VALU 54%,
// vmem-issue ~45% from 96x 4B global_load_lds per block):
//  - 16B DMAs (global_load_lds dwordx4): 4x fewer vmem instructions. Forces
//    linear 64-float LDS rows (wave-uniform dst), so the staging window is an
//    exact, 4-float-aligned, fully-in-image 64-col window (no per-lane clamp).
//  - 4 channels per block: per-pixel weight/address setup amortized 4x.
// One real stall point per block (ch0's vmcnt(9)); ch1-3 data arrives during
// ch0's gather. Counted vmcnt ladder 9/7/5/3, never drain-to-0 mid-block.
// All per-pixel fp math is bit-identical to the verified round-0..2 kernels.
constexpr int B = 16, C = 8, H = 512, W = 512;
constexpr int HW = H * W;
constexpr int TILE = 32;           // 32x32 output tile per block
constexpr int ROWS = 48;           // staged source rows (bbox span <= 46)
constexpr int CPB  = 4;            // channels per block
// Per-channel LDS chunk: [4 front pads][48*64 data][4 tail pads] floats.
// bp = chunk+4 (16B aligned). Reachable relative indices: [-1, 3072];
// bp[-1] (=chunk[3]) and bp[3072] (=chunk[3076]) are zeroed pad cells.
constexpr int CSTR = 4 + ROWS * 64 + 4;   // 3080 floats, 16B-aligned stride

// Async global->LDS, 16B/lane: per-lane global address, LDS dst =
// wave-uniform base + lane*16 (one instruction = 4 rows of 64 floats).
__device__ __forceinline__ void dma16(const float* g, float* l) {
    __builtin_amdgcn_global_load_lds(
        (const __attribute__((address_space(1))) unsigned int*)g,
        (__attribute__((address_space(3))) unsigned int*)l,
        16, 0, 0);
}

#define WAITB(n) asm volatile("s_waitcnt vmcnt(" #n ") lgkmcnt(0)\n\ts_barrier" ::: "memory")

__global__ __launch_bounds__(256, 3) void grid_sampler_kernel(
    const float* __restrict__ img,
    const float* __restrict__ params,
    float* __restrict__ out) {
    __shared__ float lds[CPB * CSTR];
    const int tid = threadIdx.x;

    // Bijective XCD swizzle: 8192 blocks = 8 XCDs x 1024. Consecutive logical
    // ids = same (batch, channel-quad), adjacent tiles (overlapping staging
    // windows) -> same XCD L2.
    const int blk = (int)blockIdx.x;
    const int l   = (blk & 7) * 1024 + (blk >> 3);
    const int b   = l >> 9;              // (b, ch-quad, ty, tx) ordering
    const int cg  = (l >> 8) & 1;
    const int tt  = l & 255;
    const int ty0 = (tt >> 4) * TILE;
    const int tx0 = (tt & 15) * TILE;

    // Zero the 2 pad cells of each channel chunk (only unstaged cells any
    // (zero-weight) tap can reach; must be finite, LDS starts uninitialized).
    if (tid < 2 * CPB) {
        const int k = tid >> 1;
        lds[k * CSTR + ((tid & 1) ? (4 + ROWS * 64) : 3)] = 0.0f;
    }

    // Wave-uniform per-batch params.
    const float tpx = params[b * 3 + 0] * (1.0f / W);
    const float tpy = params[b * 3 + 1] * (1.0f / H);
    const float th  = params[b * 3 + 2];
    const float c = cosf(th), s = sinf(th);

    // Identical fp expression for bbox corners and per-pixel sampling; gx/gy
    // monotone in x,y (per fixed other coord) so corner min bounds every pixel.
    auto srcxy = [&](float x, float y, float& ix, float& iy) {
        float xs = (2.0f * x + 1.0f) * (1.0f / W) - 1.0f;
        float ys = (2.0f * y + 1.0f) * (1.0f / H) - 1.0f;
        float gx = c * xs - s * ys + tpx;
        float gy = s * xs + c * ys + tpy;
        ix = ((gx + 1.0f) * (float)W - 1.0f) * 0.5f;
        iy = ((gy + 1.0f) * (float)H - 1.0f) * 0.5f;
    };

    float ixa, iya, ixb, iyb, ixc, iyc, ixd, iyd;
    srcxy((float)tx0,             (float)ty0,             ixa, iya);
    srcxy((float)(tx0 + TILE-1),  (float)ty0,             ixb, iyb);
    srcxy((float)tx0,             (float)(ty0 + TILE-1),  ixc, iyc);
    srcxy((float)(tx0 + TILE-1),  (float)(ty0 + TILE-1),  ixd, iyd);
    const float ixmin = fminf(fminf(ixa, ixb), fminf(ixc, ixd));
    const float iymin = fminf(fminf(iya, iyb), fminf(iyc, iyd));
    const int xlo = min(max((int)floorf(ixmin), 0), W - 1);
    const int ylo = min(max((int)floorf(iymin), 0), H - 1);
    // Exact staging window: 64 cols starting at xs0 (4-float aligned for 16B
    // DMA, fully in-image). Bbox x-span <= 44; alignment wastes <= 3 cols and
    // the 1-texel left margin <= 1, so 64 always covers every valid tap.
    const int xs0 = max(0, min((xlo - 1) & ~3, W - 64));
    const int yls = min(ylo, H - ROWS);  // rows always in-image

    // Stage all 4 channels, 16B/lane: wave wv stages rows [12wv, 12wv+12) of
    // each channel as 3 dwordx4 DMAs (lane i -> row +(i>>4), colblock i&15).
    const size_t plane = (size_t)(b * C + CPB * cg) * HW;  // channel-quad base
    const int wv = tid >> 6, ln = tid & 63;
    const float* srcL = img + plane + (size_t)yls * W + xs0
                      + (size_t)(ln >> 4) * W + (ln & 15) * 4;
#pragma unroll
    for (int k = 0; k < CPB; ++k) {
#pragma unroll
        for (int j2 = 0; j2 < 3; ++j2) {
            const int rg = 12 * wv + 4 * j2;   // row-group base (uniform)
            dma16(srcL + (size_t)k * HW + (size_t)rg * W,
                  &lds[k * CSTR + 4 + rg * 64]);
        }
    }

    // Per-pixel setup ONCE (overlaps the DMA flight), reused by 4 channels.
    const int oy  = ty0 + (tid >> 3);
    const int oxb = tx0 + (tid & 7) * 4;
    int   a0[4], a1[4];
    float w00[4], w01[4], w10[4], w11[4];
#pragma unroll
    for (int j = 0; j < 4; ++j) {
        float ix, iy;
        srcxy((float)(oxb + j), (float)oy, ix, iy);
        const float x0f = floorf(ix), y0f = floorf(iy);
        const int x0 = (int)x0f, y0 = (int)y0f;
        const int x1 = x0 + 1,  y1 = y0 + 1;
        const float wx1 = ix - x0f, wx0 = 1.0f - wx1;
        const float wy1 = iy - y0f, wy0 = 1.0f - wy1;
        const float vx0 = (x0 >= 0 && x0 < W) ? 1.0f : 0.0f;
        const float vx1 = (x1 >= 0 && x1 < W) ? 1.0f : 0.0f;
        const float vy0 = (y0 >= 0 && y0 < H) ? 1.0f : 0.0f;
        const float vy1 = (y1 >= 0 && y1 < H) ? 1.0f : 0.0f;
        w00[j] = wy0 * wx0 * vy0 * vx0;
        w01[j] = wy0 * wx1 * vy0 * vx1;
        w10[j] = wy1 * wx0 * vy1 * vx0;
        w11[j] = wy1 * wx1 * vy1 * vx1;
        // Valid x0 -> xi = x0-xs0 in [0,63] exact (window covers bbox).
        // x0=-1 (0-wt) -> xi=-1 hits the zeroed front pad; its x1 tap reads
        // bp[yi*64] = image col 0 (correct). xi=63's +1 tap hits the next
        // row's col 0 or the zeroed tail pad, always 0-weight & finite.
        const int xi  = min(max(x0 - xs0, -1), 63);
        const int yi0 = min(max(y0 - yls, 0), ROWS - 1);
        const int yi1 = min(max(y1 - yls, 0), ROWS - 1);
        a0[j] = yi0 * 64 + xi;
        a1[j] = yi1 * 64 + xi;
    }
    const int ooff = oy * W + oxb;

    auto gatherStore = [&](int k) {
        const float* bp = &lds[k * CSTR + 4];
        float4 v;
#pragma unroll
        for (int j = 0; j < 4; ++j) {
            const float t00 = bp[a0[j]], t01 = bp[a0[j] + 1];
            const float t10 = bp[a1[j]], t11 = bp[a1[j] + 1];
            ((float*)&v)[j] = t00 * w00[j] + t01 * w01[j]
                            + t10 * w10[j] + t11 * w11[j];
        }
        *(float4*)(out + plane + (size_t)k * HW + ooff) = v;
    };

    // Counted vmcnt ladder: before ch k's gather, the ops allowed in flight
    // are the (3-k)*3 younger channels' DMAs + k own stores.
    WAITB(9); gatherStore(0);
    WAITB(7); gatherStore(1);
    WAITB(5); gatherStore(2);
    WAITB(3); gatherStore(3);
}

extern "C" void kernel_launch(void* const* d_in, const int* in_sizes, int n_in,
                              void* d_out, int out_size, void* d_ws, size_t ws_size,
                              hipStream_t stream) {
    const float* img    = (const float*)d_in[0];
    const float* params = (const float*)d_in[1];
    float*       out    = (float*)d_out;

    constexpr int grid = B * (C / CPB) * (H / TILE) * (W / TILE);  // 8192
    grid_sampler_kernel<<<grid, 256, 0, stream>>>(img, params, out);
}